// Round 3
// baseline (432.195 us; speedup 1.0000x reference)
//
#include <hip/hip_runtime.h>
#include <math.h>

#define NN 20000
#define NE 640000
#define HD 128
#define NLAYERS 3
#define NPART 8
#define PART_SZ (NN / NPART)   // 2500
#define ROWS 32
#define NBLK (NN / ROWS)       // 625

// ---------------- CSR build ----------------
__global__ __launch_bounds__(256) void k_fill_zero(int* __restrict__ p, int n) {
    int t = blockIdx.x * 256 + threadIdx.x;
    if (t < n) p[t] = 0;
}

__global__ __launch_bounds__(256) void k_hist(const int* __restrict__ dst, int* __restrict__ cnt) {
    int e = blockIdx.x * 256 + threadIdx.x;
    if (e >= NE) return;
    atomicAdd(&cnt[dst[e]], 1);
}

// single block, 1024 threads, 20 items each -> exclusive scan of cnt[0..NN)
__global__ __launch_bounds__(1024) void k_scan(const int* __restrict__ cnt,
                                               int* __restrict__ row_ptr,
                                               int* __restrict__ cursor) {
    __shared__ int sums[1024];
    int t = threadIdx.x;
    int base = t * 20;
    int local[20];
    int s = 0;
#pragma unroll
    for (int i = 0; i < 20; i++) {
        int idx = base + i;
        int v = (idx < NN) ? cnt[idx] : 0;
        local[i] = s;
        s += v;
    }
    sums[t] = s;
    __syncthreads();
    for (int off = 1; off < 1024; off <<= 1) {
        int v = (t >= off) ? sums[t - off] : 0;
        __syncthreads();
        sums[t] += v;
        __syncthreads();
    }
    int offset = (t == 0) ? 0 : sums[t - 1];
#pragma unroll
    for (int i = 0; i < 20; i++) {
        int idx = base + i;
        if (idx < NN) {
            int p = offset + local[i];
            row_ptr[idx] = p;
            cursor[idx] = p;
        }
    }
    if (t == 1023) row_ptr[NN] = sums[1023];
}

// Partitioned scatter: partition = blockIdx & 7 (= XCD on round-robin dispatch)
__global__ __launch_bounds__(256) void k_scatter(const int* __restrict__ src,
                                                 const int* __restrict__ dst,
                                                 const float* __restrict__ ea,
                                                 int* __restrict__ cursor,
                                                 int2* __restrict__ edges) {
    int part = blockIdx.x & (NPART - 1);
    int blk = blockIdx.x >> 3;
    int nblk = gridDim.x >> 3;
    int lo = part * PART_SZ;
    for (int e = blk * 256 + threadIdx.x; e < NE; e += nblk * 256) {
        int d = dst[e];
        if ((unsigned)(d - lo) < (unsigned)PART_SZ) {
            int pos = atomicAdd(&cursor[d], 1);
            edges[pos] = make_int2(src[e], __float_as_int(ea[e]));
        }
    }
}

// ---------------- encoder + mm1: h = x*ew+eb; A = h@Wd+mb; B = h@Ws ----------------
// 256 threads = 2 halves of 128 cols; 32 nodes/block, 16 per half
__global__ __launch_bounds__(256) void k_enc_mm1(const float* __restrict__ x,
                                                 const float* __restrict__ enc_w,
                                                 const float* __restrict__ enc_b,
                                                 const float* __restrict__ msg_w,
                                                 const float* __restrict__ msg_b,
                                                 float* __restrict__ h,
                                                 float* __restrict__ A,
                                                 float* __restrict__ B) {
    __shared__ float hs[ROWS][HD];
    int t = threadIdx.x & 127;
    int r0 = (threadIdx.x >> 7) * 16;
    int n0 = blockIdx.x * ROWS;
    float ew = enc_w[t], eb = enc_b[t];
#pragma unroll
    for (int r = 0; r < 16; r++) {
        float v = fmaf(x[n0 + r0 + r], ew, eb);
        hs[r0 + r][t] = v;
        h[(size_t)(n0 + r0 + r) * HD + t] = v;
    }
    __syncthreads();
    float a[16], b[16];
    float mb = msg_b[t];
#pragma unroll
    for (int r = 0; r < 16; r++) { a[r] = mb; b[r] = 0.f; }
    for (int c = 0; c < HD; c += 4) {
        float wA[4], wB[4];
#pragma unroll
        for (int j = 0; j < 4; j++) {
            wA[j] = msg_w[(c + j) * HD + t];
            wB[j] = msg_w[(HD + c + j) * HD + t];
        }
#pragma unroll
        for (int r = 0; r < 16; r++) {
            float4 hv = *(const float4*)&hs[r0 + r][c];
            a[r] = fmaf(hv.x, wA[0], a[r]);
            a[r] = fmaf(hv.y, wA[1], a[r]);
            a[r] = fmaf(hv.z, wA[2], a[r]);
            a[r] = fmaf(hv.w, wA[3], a[r]);
            b[r] = fmaf(hv.x, wB[0], b[r]);
            b[r] = fmaf(hv.y, wB[1], b[r]);
            b[r] = fmaf(hv.z, wB[2], b[r]);
            b[r] = fmaf(hv.w, wB[3], b[r]);
        }
    }
#pragma unroll
    for (int r = 0; r < 16; r++) {
        A[(size_t)(n0 + r0 + r) * HD + t] = a[r];
        B[(size_t)(n0 + r0 + r) * HD + t] = b[r];
    }
}

// ---------------- aggregation: A[i] = relu(A[i] + max_e(B[src]+ea*w256)) ----------------
__global__ __launch_bounds__(128) void k_aggr(const float* __restrict__ B,
                                              float* __restrict__ A,
                                              const int* __restrict__ row_ptr,
                                              const int2* __restrict__ edges,
                                              const float* __restrict__ msg_w) {
    int i = blockIdx.x;
    int t = threadIdx.x;
    int e0 = row_ptr[i], e1 = row_ptr[i + 1];
    float w256 = msg_w[256 * HD + t];
    float m = -INFINITY;
    int e = e0;
    for (; e + 3 < e1; e += 4) {
        int2 p0 = edges[e], p1 = edges[e + 1], p2 = edges[e + 2], p3 = edges[e + 3];
        float v0 = fmaf(__int_as_float(p0.y), w256, B[(size_t)p0.x * HD + t]);
        float v1 = fmaf(__int_as_float(p1.y), w256, B[(size_t)p1.x * HD + t]);
        float v2 = fmaf(__int_as_float(p2.y), w256, B[(size_t)p2.x * HD + t]);
        float v3 = fmaf(__int_as_float(p3.y), w256, B[(size_t)p3.x * HD + t]);
        m = fmaxf(m, fmaxf(fmaxf(v0, v1), fmaxf(v2, v3)));
    }
    for (; e < e1; e++) {
        int2 p0 = edges[e];
        m = fmaxf(m, fmaf(__int_as_float(p0.y), w256, B[(size_t)p0.x * HD + t]));
    }
    A[i * HD + t] = fmaxf(A[i * HD + t] + m, 0.f);
}

// ---------------- fused update(l) + mm1(l+1) ----------------
__global__ __launch_bounds__(256) void k_mm2_mm1(const float* __restrict__ h,
                                                 const float* __restrict__ aggr,
                                                 const float* __restrict__ upd_w,
                                                 const float* __restrict__ upd_b,
                                                 const float* __restrict__ msg_w,
                                                 const float* __restrict__ msg_b,
                                                 float* __restrict__ hout,
                                                 float* __restrict__ A,
                                                 float* __restrict__ B) {
    __shared__ float hs[ROWS][HD];
    __shared__ float as[ROWS][HD];
    int t = threadIdx.x & 127;
    int r0 = (threadIdx.x >> 7) * 16;
    int n0 = blockIdx.x * ROWS;
#pragma unroll
    for (int r = 0; r < 16; r++) {
        hs[r0 + r][t] = h[(size_t)(n0 + r0 + r) * HD + t];
        as[r0 + r][t] = aggr[(size_t)(n0 + r0 + r) * HD + t];
    }
    __syncthreads();
    float acc[16];
    float ub = upd_b[t];
#pragma unroll
    for (int r = 0; r < 16; r++) acc[r] = ub;
    for (int c = 0; c < HD; c += 4) {
        float w1[4], w2[4];
#pragma unroll
        for (int j = 0; j < 4; j++) {
            w1[j] = upd_w[(c + j) * HD + t];
            w2[j] = upd_w[(HD + c + j) * HD + t];
        }
#pragma unroll
        for (int r = 0; r < 16; r++) {
            float4 hv = *(const float4*)&hs[r0 + r][c];
            float4 av = *(const float4*)&as[r0 + r][c];
            acc[r] = fmaf(hv.x, w1[0], acc[r]);
            acc[r] = fmaf(hv.y, w1[1], acc[r]);
            acc[r] = fmaf(hv.z, w1[2], acc[r]);
            acc[r] = fmaf(hv.w, w1[3], acc[r]);
            acc[r] = fmaf(av.x, w2[0], acc[r]);
            acc[r] = fmaf(av.y, w2[1], acc[r]);
            acc[r] = fmaf(av.z, w2[2], acc[r]);
            acc[r] = fmaf(av.w, w2[3], acc[r]);
        }
    }
    __syncthreads();   // all reads of hs done before overwrite
#pragma unroll
    for (int r = 0; r < 16; r++) {
        float v = fmaxf(acc[r], 0.f);
        hout[(size_t)(n0 + r0 + r) * HD + t] = v;
        hs[r0 + r][t] = v;
    }
    __syncthreads();
    float a[16], b[16];
    float mb = msg_b[t];
#pragma unroll
    for (int r = 0; r < 16; r++) { a[r] = mb; b[r] = 0.f; }
    for (int c = 0; c < HD; c += 4) {
        float wA[4], wB[4];
#pragma unroll
        for (int j = 0; j < 4; j++) {
            wA[j] = msg_w[(c + j) * HD + t];
            wB[j] = msg_w[(HD + c + j) * HD + t];
        }
#pragma unroll
        for (int r = 0; r < 16; r++) {
            float4 hv = *(const float4*)&hs[r0 + r][c];
            a[r] = fmaf(hv.x, wA[0], a[r]);
            a[r] = fmaf(hv.y, wA[1], a[r]);
            a[r] = fmaf(hv.z, wA[2], a[r]);
            a[r] = fmaf(hv.w, wA[3], a[r]);
            b[r] = fmaf(hv.x, wB[0], b[r]);
            b[r] = fmaf(hv.y, wB[1], b[r]);
            b[r] = fmaf(hv.z, wB[2], b[r]);
            b[r] = fmaf(hv.w, wB[3], b[r]);
        }
    }
#pragma unroll
    for (int r = 0; r < 16; r++) {
        A[(size_t)(n0 + r0 + r) * HD + t] = a[r];
        B[(size_t)(n0 + r0 + r) * HD + t] = b[r];
    }
}

// ---------------- final update + decoder + term partial ----------------
__global__ __launch_bounds__(256) void k_mm2_dec(const float* __restrict__ h,
                                                 const float* __restrict__ aggr,
                                                 const float* __restrict__ upd_w,
                                                 const float* __restrict__ upd_b,
                                                 const float* __restrict__ dec_w,
                                                 const float* __restrict__ dec_b,
                                                 const float* __restrict__ term_w,
                                                 float* __restrict__ out,
                                                 float* __restrict__ partials) {
    __shared__ float hs[ROWS][HD];
    __shared__ float as[ROWS][HD];
    __shared__ float tred[4];
    int t = threadIdx.x & 127;
    int r0 = (threadIdx.x >> 7) * 16;
    int n0 = blockIdx.x * ROWS;
#pragma unroll
    for (int r = 0; r < 16; r++) {
        hs[r0 + r][t] = h[(size_t)(n0 + r0 + r) * HD + t];
        as[r0 + r][t] = aggr[(size_t)(n0 + r0 + r) * HD + t];
    }
    __syncthreads();
    float acc[16];
    float ub = upd_b[t];
#pragma unroll
    for (int r = 0; r < 16; r++) acc[r] = ub;
    for (int c = 0; c < HD; c += 4) {
        float w1[4], w2[4];
#pragma unroll
        for (int j = 0; j < 4; j++) {
            w1[j] = upd_w[(c + j) * HD + t];
            w2[j] = upd_w[(HD + c + j) * HD + t];
        }
#pragma unroll
        for (int r = 0; r < 16; r++) {
            float4 hv = *(const float4*)&hs[r0 + r][c];
            float4 av = *(const float4*)&as[r0 + r][c];
            acc[r] = fmaf(hv.x, w1[0], acc[r]);
            acc[r] = fmaf(hv.y, w1[1], acc[r]);
            acc[r] = fmaf(hv.z, w1[2], acc[r]);
            acc[r] = fmaf(hv.w, w1[3], acc[r]);
            acc[r] = fmaf(av.x, w2[0], acc[r]);
            acc[r] = fmaf(av.y, w2[1], acc[r]);
            acc[r] = fmaf(av.z, w2[2], acc[r]);
            acc[r] = fmaf(av.w, w2[3], acc[r]);
        }
    }
    __syncthreads();
#pragma unroll
    for (int r = 0; r < 16; r++) hs[r0 + r][t] = fmaxf(acc[r], 0.f);
    __syncthreads();
    // decoder + term: wave w reduces rows w*8 .. w*8+7
    int wave = threadIdx.x >> 6, lane = threadIdx.x & 63;
    float dw0 = dec_w[lane], dw1 = dec_w[64 + lane];
    float tw0 = term_w[lane], tw1 = term_w[64 + lane];
    float tsum = 0.f;
#pragma unroll
    for (int rr = 0; rr < 8; rr++) {
        int r = wave * 8 + rr;
        float h0 = hs[r][lane], h1 = hs[r][64 + lane];
        float s1 = fmaf(h0, dw0, h1 * dw1);
        float s2 = fmaf(h0, tw0, h1 * tw1);
#pragma unroll
        for (int off = 32; off; off >>= 1) {
            s1 += __shfl_xor(s1, off);
            s2 += __shfl_xor(s2, off);
        }
        if (lane == 0) out[n0 + r] = 1.f / (1.f + expf(-(s1 + dec_b[0])));
        tsum += s2;
    }
    if (lane == 0) tred[wave] = tsum;
    __syncthreads();
    if (threadIdx.x == 0) partials[blockIdx.x] = tred[0] + tred[1] + tred[2] + tred[3];
}

__global__ __launch_bounds__(256) void k_term(const float* __restrict__ partials,
                                              const float* __restrict__ term_b,
                                              float* __restrict__ out) {
    __shared__ float red[256];
    int t = threadIdx.x;
    float s = 0.f;
    for (int i = t; i < NBLK; i += 256) s += partials[i];
    red[t] = s;
    __syncthreads();
    for (int off = 128; off; off >>= 1) {
        if (t < off) red[t] += red[t + off];
        __syncthreads();
    }
    if (t == 0) {
        float m = red[0] / (float)NN;
        out[NN] = 1.f / (1.f + expf(-(m + term_b[0])));
    }
}

extern "C" void kernel_launch(void* const* d_in, const int* in_sizes, int n_in,
                              void* d_out, int out_size, void* d_ws, size_t ws_size,
                              hipStream_t stream) {
    const float* x        = (const float*)d_in[0];
    const int*   eidx     = (const int*)d_in[1];
    const float* eattr    = (const float*)d_in[2];
    const float* enc_w    = (const float*)d_in[3];
    const float* enc_b    = (const float*)d_in[4];
    const float* msg_w    = (const float*)d_in[5];
    const float* msg_b    = (const float*)d_in[6];
    const float* upd_w    = (const float*)d_in[7];
    const float* upd_b    = (const float*)d_in[8];
    const float* dec_w    = (const float*)d_in[9];
    const float* dec_b    = (const float*)d_in[10];
    const float* term_w   = (const float*)d_in[11];
    const float* term_b   = (const float*)d_in[12];
    float* out = (float*)d_out;

    const int* src = eidx;          // edge_index[0] = source j
    const int* dst = eidx + NE;     // edge_index[1] = target i

    char* ws = (char*)d_ws;
    size_t off = 0;
    auto alloc = [&](size_t bytes) -> void* {
        void* p = ws + off;
        off += (bytes + 255) & ~size_t(255);
        return p;
    };
    float* hA        = (float*)alloc((size_t)NN * HD * 4);
    float* hB        = (float*)alloc((size_t)NN * HD * 4);
    float* Abuf      = (float*)alloc((size_t)NN * HD * 4);
    float* Bbuf      = (float*)alloc((size_t)NN * HD * 4);
    int2*  edges     = (int2*) alloc((size_t)NE * 8);
    int*   row_ptr   = (int*)  alloc((size_t)(NN + 1) * 4);
    int*   cnt       = (int*)  alloc((size_t)NN * 4);
    int*   cursor    = (int*)  alloc((size_t)NN * 4);
    float* partials  = (float*)alloc((size_t)NBLK * 4);

    // CSR build (by dst)
    k_fill_zero<<<(NN + 255) / 256, 256, 0, stream>>>(cnt, NN);
    k_hist<<<(NE + 255) / 256, 256, 0, stream>>>(dst, cnt);
    k_scan<<<1, 1024, 0, stream>>>(cnt, row_ptr, cursor);
    k_scatter<<<NPART * 128, 256, 0, stream>>>(src, dst, eattr, cursor, edges);

    // encoder + first message linear
    k_enc_mm1<<<NBLK, 256, 0, stream>>>(x, enc_w, enc_b, msg_w, msg_b, hA, Abuf, Bbuf);

    float* hin = hA;
    float* hout = hB;
    for (int l = 0; l < NLAYERS; l++) {
        k_aggr<<<NN, 128, 0, stream>>>(Bbuf, Abuf, row_ptr, edges, msg_w);
        if (l < NLAYERS - 1) {
            k_mm2_mm1<<<NBLK, 256, 0, stream>>>(hin, Abuf, upd_w, upd_b, msg_w, msg_b,
                                                hout, Abuf, Bbuf);
            float* tmp = hin; hin = hout; hout = tmp;
        } else {
            k_mm2_dec<<<NBLK, 256, 0, stream>>>(hin, Abuf, upd_w, upd_b,
                                                dec_w, dec_b, term_w, out, partials);
        }
    }
    k_term<<<1, 256, 0, stream>>>(partials, term_b, out);
}

// Round 5
// 388.442 us; speedup vs baseline: 1.1126x; 1.1126x over previous
//
#include <hip/hip_runtime.h>
#include <math.h>

#define NN 20000
#define NE 640000
#define HD 128
#define NLAYERS 3
#define NPART 8
#define PART_SZ (NN / NPART)   // 2500
#define ROWS 16
#define NBLK (NN / ROWS)       // 1250

__device__ __forceinline__ void fma4(float4& acc, float s, const float4& v) {
    acc.x = fmaf(s, v.x, acc.x);
    acc.y = fmaf(s, v.y, acc.y);
    acc.z = fmaf(s, v.z, acc.z);
    acc.w = fmaf(s, v.w, acc.w);
}

// ---------------- CSR build ----------------
__global__ __launch_bounds__(256) void k_fill_zero(int* __restrict__ p, int n) {
    int t = blockIdx.x * 256 + threadIdx.x;
    if (t < n) p[t] = 0;
}

__global__ __launch_bounds__(256) void k_hist(const int* __restrict__ dst, int* __restrict__ cnt) {
    int e = blockIdx.x * 256 + threadIdx.x;
    if (e >= NE) return;
    atomicAdd(&cnt[dst[e]], 1);
}

__global__ __launch_bounds__(1024) void k_scan(const int* __restrict__ cnt,
                                               int* __restrict__ row_ptr,
                                               int* __restrict__ cursor) {
    __shared__ int sums[1024];
    int t = threadIdx.x;
    int base = t * 20;
    int local[20];
    int s = 0;
#pragma unroll
    for (int i = 0; i < 20; i++) {
        int idx = base + i;
        int v = (idx < NN) ? cnt[idx] : 0;
        local[i] = s;
        s += v;
    }
    sums[t] = s;
    __syncthreads();
    for (int off = 1; off < 1024; off <<= 1) {
        int v = (t >= off) ? sums[t - off] : 0;
        __syncthreads();
        sums[t] += v;
        __syncthreads();
    }
    int offset = (t == 0) ? 0 : sums[t - 1];
#pragma unroll
    for (int i = 0; i < 20; i++) {
        int idx = base + i;
        if (idx < NN) {
            int p = offset + local[i];
            row_ptr[idx] = p;
            cursor[idx] = p;
        }
    }
    if (t == 1023) row_ptr[NN] = sums[1023];
}

__global__ __launch_bounds__(256) void k_scatter(const int* __restrict__ src,
                                                 const int* __restrict__ dst,
                                                 const float* __restrict__ ea,
                                                 int* __restrict__ cursor,
                                                 int2* __restrict__ edges) {
    int part = blockIdx.x & (NPART - 1);
    int blk = blockIdx.x >> 3;
    int nblk = gridDim.x >> 3;
    int lo = part * PART_SZ;
    for (int e = blk * 256 + threadIdx.x; e < NE; e += nblk * 256) {
        int d = dst[e];
        if ((unsigned)(d - lo) < (unsigned)PART_SZ) {
            int pos = atomicAdd(&cursor[d], 1);
            edges[pos] = make_int2(src[e], __float_as_int(ea[e]));
        }
    }
}

// ---------------- register-tiled GEMM helpers ----------------
// S: LDS [ROWS][HD]; W: row-major [HD][HD]; thread (tc,tr) computes
// rows tr*4..+3, cols tc*4..+3 into float4 acc[4].
__device__ __forceinline__ void gemm_acc(const float (*S)[HD], const float* __restrict__ W,
                                         int tc, int tr, float4 acc[4]) {
    float4 w[4], wn[4];
#pragma unroll
    for (int j = 0; j < 4; j++) w[j] = *(const float4*)&W[j * HD + tc * 4];
    for (int k = 0; k < HD; k += 4) {
        if (k + 4 < HD) {
#pragma unroll
            for (int j = 0; j < 4; j++) wn[j] = *(const float4*)&W[(k + 4 + j) * HD + tc * 4];
        }
#pragma unroll
        for (int r = 0; r < 4; r++) {
            float4 hv = *(const float4*)&S[tr * 4 + r][k];
            fma4(acc[r], hv.x, w[0]);
            fma4(acc[r], hv.y, w[1]);
            fma4(acc[r], hv.z, w[2]);
            fma4(acc[r], hv.w, w[3]);
        }
#pragma unroll
        for (int j = 0; j < 4; j++) w[j] = wn[j];
    }
}

// dual-output version: a += S@WA, b += S@WB (shares the S reads)
__device__ __forceinline__ void gemm_acc2(const float (*S)[HD],
                                          const float* __restrict__ WA,
                                          const float* __restrict__ WB,
                                          int tc, int tr, float4 a[4], float4 b[4]) {
    float4 wa[4], wb[4], wan[4], wbn[4];
#pragma unroll
    for (int j = 0; j < 4; j++) {
        wa[j] = *(const float4*)&WA[j * HD + tc * 4];
        wb[j] = *(const float4*)&WB[j * HD + tc * 4];
    }
    for (int k = 0; k < HD; k += 4) {
        if (k + 4 < HD) {
#pragma unroll
            for (int j = 0; j < 4; j++) {
                wan[j] = *(const float4*)&WA[(k + 4 + j) * HD + tc * 4];
                wbn[j] = *(const float4*)&WB[(k + 4 + j) * HD + tc * 4];
            }
        }
#pragma unroll
        for (int r = 0; r < 4; r++) {
            float4 hv = *(const float4*)&S[tr * 4 + r][k];
            fma4(a[r], hv.x, wa[0]);
            fma4(b[r], hv.x, wb[0]);
            fma4(a[r], hv.y, wa[1]);
            fma4(b[r], hv.y, wb[1]);
            fma4(a[r], hv.z, wa[2]);
            fma4(b[r], hv.z, wb[2]);
            fma4(a[r], hv.w, wa[3]);
            fma4(b[r], hv.w, wb[3]);
        }
#pragma unroll
        for (int j = 0; j < 4; j++) { wa[j] = wan[j]; wb[j] = wbn[j]; }
    }
}

// ---------------- encoder + mm1 ----------------
__global__ __launch_bounds__(128) void k_enc_mm1(const float* __restrict__ x,
                                                 const float* __restrict__ enc_w,
                                                 const float* __restrict__ enc_b,
                                                 const float* __restrict__ msg_w,
                                                 const float* __restrict__ msg_b,
                                                 float* __restrict__ h,
                                                 float* __restrict__ A,
                                                 float* __restrict__ B) {
    __shared__ float hs[ROWS][HD];
    int t = threadIdx.x;
    int tc = t & 31, tr = t >> 5;
    int n0 = blockIdx.x * ROWS;
    {
        float ew = enc_w[t], eb = enc_b[t];
#pragma unroll
        for (int r = 0; r < ROWS; r++) {
            float v = fmaf(x[n0 + r], ew, eb);
            hs[r][t] = v;
            h[(size_t)(n0 + r) * HD + t] = v;
        }
    }
    __syncthreads();
    float4 a[4], b[4];
    float4 mb = *(const float4*)&msg_b[tc * 4];
#pragma unroll
    for (int r = 0; r < 4; r++) { a[r] = mb; b[r] = make_float4(0.f, 0.f, 0.f, 0.f); }
    gemm_acc2(hs, msg_w, msg_w + HD * HD, tc, tr, a, b);
#pragma unroll
    for (int r = 0; r < 4; r++) {
        int row = n0 + tr * 4 + r;
        *(float4*)&A[(size_t)row * HD + tc * 4] = a[r];
        *(float4*)&B[(size_t)row * HD + tc * 4] = b[r];
    }
}

// ---------------- aggregation: A[i] = relu(A[i] + max_e(B[src]+ea*w256)) ----------------
__global__ __launch_bounds__(128) void k_aggr(const float* __restrict__ B,
                                              float* __restrict__ A,
                                              const int* __restrict__ row_ptr,
                                              const int2* __restrict__ edges,
                                              const float* __restrict__ msg_w) {
    int i = blockIdx.x;
    int t = threadIdx.x;
    int e0 = row_ptr[i], e1 = row_ptr[i + 1];
    float w256 = msg_w[256 * HD + t];
    float m = -INFINITY;
    int e = e0;
    for (; e + 3 < e1; e += 4) {
        int2 p0 = edges[e], p1 = edges[e + 1], p2 = edges[e + 2], p3 = edges[e + 3];
        float v0 = fmaf(__int_as_float(p0.y), w256, B[(size_t)p0.x * HD + t]);
        float v1 = fmaf(__int_as_float(p1.y), w256, B[(size_t)p1.x * HD + t]);
        float v2 = fmaf(__int_as_float(p2.y), w256, B[(size_t)p2.x * HD + t]);
        float v3 = fmaf(__int_as_float(p3.y), w256, B[(size_t)p3.x * HD + t]);
        m = fmaxf(m, fmaxf(fmaxf(v0, v1), fmaxf(v2, v3)));
    }
    for (; e < e1; e++) {
        int2 p0 = edges[e];
        m = fmaxf(m, fmaf(__int_as_float(p0.y), w256, B[(size_t)p0.x * HD + t]));
    }
    A[i * HD + t] = fmaxf(A[i * HD + t] + m, 0.f);
}

// ---------------- fused update(l) + mm1(l+1) ----------------
__global__ __launch_bounds__(128) void k_mm2_mm1(const float* __restrict__ h,
                                                 const float* __restrict__ aggr,
                                                 const float* __restrict__ upd_w,
                                                 const float* __restrict__ upd_b,
                                                 const float* __restrict__ msg_w,
                                                 const float* __restrict__ msg_b,
                                                 float* __restrict__ hout,
                                                 float* __restrict__ A,
                                                 float* __restrict__ B) {
    __shared__ float hs[ROWS][HD];
    __shared__ float as_[ROWS][HD];
    int t = threadIdx.x;
    int tc = t & 31, tr = t >> 5;
    int n0 = blockIdx.x * ROWS;
#pragma unroll
    for (int i = 0; i < 4; i++) {
        int r = tr + i * 4;
        *(float4*)&hs[r][tc * 4]  = *(const float4*)&h[(size_t)(n0 + r) * HD + tc * 4];
        *(float4*)&as_[r][tc * 4] = *(const float4*)&aggr[(size_t)(n0 + r) * HD + tc * 4];
    }
    __syncthreads();
    float4 acc[4];
    float4 ub = *(const float4*)&upd_b[tc * 4];
#pragma unroll
    for (int r = 0; r < 4; r++) acc[r] = ub;
    gemm_acc(hs, upd_w, tc, tr, acc);
    gemm_acc(as_, upd_w + HD * HD, tc, tr, acc);
    __syncthreads();   // everyone done reading hs before overwrite
#pragma unroll
    for (int r = 0; r < 4; r++) {
        acc[r].x = fmaxf(acc[r].x, 0.f);
        acc[r].y = fmaxf(acc[r].y, 0.f);
        acc[r].z = fmaxf(acc[r].z, 0.f);
        acc[r].w = fmaxf(acc[r].w, 0.f);
        int row = tr * 4 + r;
        *(float4*)&hs[row][tc * 4] = acc[r];
        *(float4*)&hout[(size_t)(n0 + row) * HD + tc * 4] = acc[r];
    }
    __syncthreads();
    float4 a[4], b[4];
    float4 mb = *(const float4*)&msg_b[tc * 4];
#pragma unroll
    for (int r = 0; r < 4; r++) { a[r] = mb; b[r] = make_float4(0.f, 0.f, 0.f, 0.f); }
    gemm_acc2(hs, msg_w, msg_w + HD * HD, tc, tr, a, b);
#pragma unroll
    for (int r = 0; r < 4; r++) {
        int row = n0 + tr * 4 + r;
        *(float4*)&A[(size_t)row * HD + tc * 4] = a[r];
        *(float4*)&B[(size_t)row * HD + tc * 4] = b[r];
    }
}

// ---------------- final update + decoder + term partial ----------------
__global__ __launch_bounds__(128) void k_mm2_dec(const float* __restrict__ h,
                                                 const float* __restrict__ aggr,
                                                 const float* __restrict__ upd_w,
                                                 const float* __restrict__ upd_b,
                                                 const float* __restrict__ dec_w,
                                                 const float* __restrict__ dec_b,
                                                 const float* __restrict__ term_w,
                                                 float* __restrict__ out,
                                                 float* __restrict__ partials) {
    __shared__ float hs[ROWS][HD];
    __shared__ float as_[ROWS][HD];
    __shared__ float tred[2];
    int t = threadIdx.x;
    int tc = t & 31, tr = t >> 5;
    int n0 = blockIdx.x * ROWS;
#pragma unroll
    for (int i = 0; i < 4; i++) {
        int r = tr + i * 4;
        *(float4*)&hs[r][tc * 4]  = *(const float4*)&h[(size_t)(n0 + r) * HD + tc * 4];
        *(float4*)&as_[r][tc * 4] = *(const float4*)&aggr[(size_t)(n0 + r) * HD + tc * 4];
    }
    __syncthreads();
    float4 acc[4];
    float4 ub = *(const float4*)&upd_b[tc * 4];
#pragma unroll
    for (int r = 0; r < 4; r++) acc[r] = ub;
    gemm_acc(hs, upd_w, tc, tr, acc);
    gemm_acc(as_, upd_w + HD * HD, tc, tr, acc);
    __syncthreads();
#pragma unroll
    for (int r = 0; r < 4; r++) {
        acc[r].x = fmaxf(acc[r].x, 0.f);
        acc[r].y = fmaxf(acc[r].y, 0.f);
        acc[r].z = fmaxf(acc[r].z, 0.f);
        acc[r].w = fmaxf(acc[r].w, 0.f);
        *(float4*)&hs[tr * 4 + r][tc * 4] = acc[r];
    }
    __syncthreads();
    // decoder + term: wave w reduces rows w*8 .. w*8+7 (ROWS=16, 2 waves)
    int wave = t >> 6, lane = t & 63;
    float dw0 = dec_w[lane], dw1 = dec_w[64 + lane];
    float tw0 = term_w[lane], tw1 = term_w[64 + lane];
    float tsum = 0.f;
#pragma unroll
    for (int rr = 0; rr < 8; rr++) {
        int r = wave * 8 + rr;
        float h0 = hs[r][lane], h1 = hs[r][64 + lane];
        float s1 = fmaf(h0, dw0, h1 * dw1);
        float s2 = fmaf(h0, tw0, h1 * tw1);
#pragma unroll
        for (int off = 32; off; off >>= 1) {
            s1 += __shfl_xor(s1, off);
            s2 += __shfl_xor(s2, off);
        }
        if (lane == 0) out[n0 + r] = 1.f / (1.f + expf(-(s1 + dec_b[0])));
        tsum += s2;
    }
    if (lane == 0) tred[wave] = tsum;
    __syncthreads();
    if (t == 0) partials[blockIdx.x] = tred[0] + tred[1];
}

__global__ __launch_bounds__(256) void k_term(const float* __restrict__ partials,
                                              const float* __restrict__ term_b,
                                              float* __restrict__ out) {
    __shared__ float red[256];
    int t = threadIdx.x;
    float s = 0.f;
    for (int i = t; i < NBLK; i += 256) s += partials[i];
    red[t] = s;
    __syncthreads();
    for (int off = 128; off; off >>= 1) {
        if (t < off) red[t] += red[t + off];
        __syncthreads();
    }
    if (t == 0) {
        float m = red[0] / (float)NN;
        out[NN] = 1.f / (1.f + expf(-(m + term_b[0])));
    }
}

extern "C" void kernel_launch(void* const* d_in, const int* in_sizes, int n_in,
                              void* d_out, int out_size, void* d_ws, size_t ws_size,
                              hipStream_t stream) {
    const float* x        = (const float*)d_in[0];
    const int*   eidx     = (const int*)d_in[1];
    const float* eattr    = (const float*)d_in[2];
    const float* enc_w    = (const float*)d_in[3];
    const float* enc_b    = (const float*)d_in[4];
    const float* msg_w    = (const float*)d_in[5];
    const float* msg_b    = (const float*)d_in[6];
    const float* upd_w    = (const float*)d_in[7];
    const float* upd_b    = (const float*)d_in[8];
    const float* dec_w    = (const float*)d_in[9];
    const float* dec_b    = (const float*)d_in[10];
    const float* term_w   = (const float*)d_in[11];
    const float* term_b   = (const float*)d_in[12];
    float* out = (float*)d_out;

    const int* src = eidx;          // edge_index[0] = source j
    const int* dst = eidx + NE;     // edge_index[1] = target i

    char* ws = (char*)d_ws;
    size_t off = 0;
    auto alloc = [&](size_t bytes) -> void* {
        void* p = ws + off;
        off += (bytes + 255) & ~size_t(255);
        return p;
    };
    float* hA        = (float*)alloc((size_t)NN * HD * 4);
    float* hB        = (float*)alloc((size_t)NN * HD * 4);
    float* Abuf      = (float*)alloc((size_t)NN * HD * 4);
    float* Bbuf      = (float*)alloc((size_t)NN * HD * 4);
    int2*  edges     = (int2*) alloc((size_t)NE * 8);
    int*   row_ptr   = (int*)  alloc((size_t)(NN + 1) * 4);
    int*   cnt       = (int*)  alloc((size_t)NN * 4);
    int*   cursor    = (int*)  alloc((size_t)NN * 4);
    float* partials  = (float*)alloc((size_t)NBLK * 4);

    // CSR build (by dst)
    k_fill_zero<<<(NN + 255) / 256, 256, 0, stream>>>(cnt, NN);
    k_hist<<<(NE + 255) / 256, 256, 0, stream>>>(dst, cnt);
    k_scan<<<1, 1024, 0, stream>>>(cnt, row_ptr, cursor);
    k_scatter<<<NPART * 128, 256, 0, stream>>>(src, dst, eattr, cursor, edges);

    // encoder + first message linear
    k_enc_mm1<<<NBLK, 128, 0, stream>>>(x, enc_w, enc_b, msg_w, msg_b, hA, Abuf, Bbuf);

    float* hin = hA;
    float* hout = hB;
    for (int l = 0; l < NLAYERS; l++) {
        k_aggr<<<NN, 128, 0, stream>>>(Bbuf, Abuf, row_ptr, edges, msg_w);
        if (l < NLAYERS - 1) {
            k_mm2_mm1<<<NBLK, 128, 0, stream>>>(hin, Abuf, upd_w, upd_b, msg_w, msg_b,
                                                hout, Abuf, Bbuf);
            float* tmp = hin; hin = hout; hout = tmp;
        } else {
            k_mm2_dec<<<NBLK, 128, 0, stream>>>(hin, Abuf, upd_w, upd_b,
                                                dec_w, dec_b, term_w, out, partials);
        }
    }
    k_term<<<1, 256, 0, stream>>>(partials, term_b, out);
}